// Round 2
// baseline (428.763 us; speedup 1.0000x reference)
//
#include <hip/hip_runtime.h>
#include <hip/hip_bf16.h>

// ---------------- sizes ----------------
#define B 16
#define L1 509
#define C1 32
#define N1 (B*L1)
#define LP1 254
#define L4 250
#define C4 64
#define N4 (B*L4)
#define LP4 125
#define L5 123
#define C5 32
#define N5 (B*L5)
#define NPOS 3936
#define CA 5
#define OUT0_ELEMS (B*CA*NPOS)   // 314880
#define FLAT_K 19680
#define F1 1024
// fc1 split-K
#define KSPLIT 8
#define KCHUNK 2460              // 19680/8

// stats layout (floats) at ws offset 0
#define S1_SUM 0
#define S1_SQ  32
#define S4_SUM 64
#define S4_SQ  128
#define S5_SUM 192
#define S5_SQ  224
#define STATS_FLOATS 256

// ---------------- helpers ----------------
__device__ __forceinline__ float elu1(float x) {
  return x > 0.f ? x : (expf(x) - 1.f);
}

__device__ __forceinline__ void block_reduce2_atomic(float v1, float v2, float* d1, float* d2) {
  #pragma unroll
  for (int off = 32; off > 0; off >>= 1) {
    v1 += __shfl_down(v1, off);
    v2 += __shfl_down(v2, off);
  }
  __shared__ float s1[8], s2[8];
  int lane = threadIdx.x & 63, w = threadIdx.x >> 6;
  if (lane == 0) { s1[w] = v1; s2[w] = v2; }
  __syncthreads();
  if (threadIdx.x == 0) {
    int nw = (blockDim.x + 63) >> 6;
    float a = 0.f, bb = 0.f;
    for (int i = 0; i < nw; i++) { a += s1[i]; bb += s2[i]; }
    atomicAdd(d1, a);
    atomicAdd(d2, bb);
  }
}

// ---------------- conv stages ----------------
__global__ void k_conv1(const float* __restrict__ x, const float* __restrict__ w,
                        const float* __restrict__ bias, float* __restrict__ y1,
                        float* __restrict__ stats) {
  int l = blockIdx.x * blockDim.x + threadIdx.x;
  int co = blockIdx.y, b = blockIdx.z;
  float v = 0.f;
  if (l < L1) {
    v = bias[co];
    const float* xp = x + b * 5 * 1021;
    const float* wp = w + co * 25;
    #pragma unroll
    for (int ci = 0; ci < 5; ci++)
      #pragma unroll
      for (int t = 0; t < 5; t++)
        v += xp[ci * 1021 + 2 * l + t] * wp[ci * 5 + t];
    y1[(b * C1 + co) * L1 + l] = v;
  }
  block_reduce2_atomic(v, v * v, &stats[S1_SUM + co], &stats[S1_SQ + co]);
}

__global__ void k_bnpool(const float* __restrict__ y, float* __restrict__ p,
                         const float* __restrict__ g, const float* __restrict__ be,
                         const float* __restrict__ ssum, const float* __restrict__ ssq,
                         int C, int Lin, int Lout, float invN) {
  int i = blockIdx.x * blockDim.x + threadIdx.x;
  int co = blockIdx.y, b = blockIdx.z;
  if (i >= Lout) return;
  float mean = ssum[co] * invN;
  float var  = ssq[co] * invN - mean * mean;
  float sc = rsqrtf(var + 1e-5f) * g[co];
  float bb = be[co];
  const float* yp = y + (b * C + co) * Lin;
  float a0 = (yp[2 * i]     - mean) * sc + bb;
  float a1 = (yp[2 * i + 1] - mean) * sc + bb;
  p[(b * C + co) * Lout + i] = fmaxf(elu1(a0), elu1(a1));
}

__global__ void k_conv4(const float* __restrict__ p1, const float* __restrict__ w,
                        const float* __restrict__ bias, float* __restrict__ y4,
                        float* __restrict__ stats) {
  int l = threadIdx.x;  // block 256, 250 active
  int co = blockIdx.y, b = blockIdx.z;
  float v = 0.f;
  if (l < L4) {
    v = bias[co];
    const float* pp = p1 + b * C1 * LP1;
    const float* wp = w + co * (C1 * 5);
    for (int ci = 0; ci < C1; ci++) {
      #pragma unroll
      for (int t = 0; t < 5; t++)
        v += pp[ci * LP1 + l + t] * wp[ci * 5 + t];
    }
    y4[(b * C4 + co) * L4 + l] = v;
  }
  block_reduce2_atomic(v, v * v, &stats[S4_SUM + co], &stats[S4_SQ + co]);
}

__global__ void k_conv5(const float* __restrict__ p4, const float* __restrict__ w,
                        const float* __restrict__ bias, float* __restrict__ y5,
                        float* __restrict__ stats) {
  int l = threadIdx.x;  // block 128, 123 active
  int co = blockIdx.y, b = blockIdx.z;
  float v = 0.f;
  if (l < L5) {
    v = bias[co];
    const float* pp = p4 + b * C4 * LP4;
    const float* wp = w + co * (C4 * 3);
    for (int ci = 0; ci < C4; ci++) {
      #pragma unroll
      for (int t = 0; t < 3; t++)
        v += pp[ci * LP4 + l + t] * wp[ci * 3 + t];
    }
    y5[(b * C5 + co) * L5 + l] = v;
  }
  block_reduce2_atomic(v, v * v, &stats[S5_SUM + co], &stats[S5_SQ + co]);
}

// tail: if both gammas are 0 the two attentions are identities; write flat directly.
// flat[b, c*3936 + h*123 + w] = elu(bn5(y5[b,h,w]))   (broadcast over c)
// else: build out0[b,c,w,h] for the generic attn kernels.
__global__ void k_tail(const float* __restrict__ y5, float* __restrict__ out0,
                       float* __restrict__ flat,
                       const float* __restrict__ g, const float* __restrict__ be,
                       const float* __restrict__ stats,
                       const float* __restrict__ ga1, const float* __restrict__ ga2) {
  int idx = blockIdx.x * 256 + threadIdx.x;
  if (idx >= OUT0_ELEMS) return;
  bool fast = (ga1[0] == 0.f) && (ga2[0] == 0.f);
  if (fast) {
    int b = idx / FLAT_K;
    int r = idx - b * FLAT_K;
    int n2 = r % NPOS;          // c broadcast: value independent of c
    int h = n2 / 123;
    int w_ = n2 - h * 123;
    float mean = stats[S5_SUM + h] * (1.f / N5);
    float var  = stats[S5_SQ + h] * (1.f / N5) - mean * mean;
    float sc = rsqrtf(var + 1e-5f) * g[h];
    float v = (y5[(b * C5 + h) * L5 + w_] - mean) * sc + be[h];
    flat[idx] = elu1(v);
  } else {
    int h = idx & 31;
    int rest = idx >> 5;        // (b*5+c)*123 + w
    int w_ = rest % 123;
    int bc = rest / 123;
    int b = bc / 5;
    float mean = stats[S5_SUM + h] * (1.f / N5);
    float var  = stats[S5_SQ + h] * (1.f / N5) - mean * mean;
    float sc = rsqrtf(var + 1e-5f) * g[h];
    float v = (y5[(b * C5 + h) * L5 + w_] - mean) * sc + be[h];
    out0[idx] = elu1(v);
  }
}

// ---------------- generic attention (only runs when a gamma != 0) ----------------
__global__ void k_attn1(const float* __restrict__ x0, float* __restrict__ out1,
                        const float* __restrict__ wq, const float* __restrict__ bq,
                        const float* __restrict__ wk, const float* __restrict__ bk,
                        const float* __restrict__ wv, const float* __restrict__ bv,
                        const float* __restrict__ gamma_p, const float* __restrict__ gamma2_p) {
  float gamma = gamma_p[0];
  if (gamma == 0.f && gamma2_p[0] == 0.f) return;   // fused fast path already done
  int idx = blockIdx.x * 256 + threadIdx.x;
  if (gamma == 0.f) {
    if (idx < OUT0_ELEMS) out1[idx] = x0[idx];
    return;
  }
  if (idx >= B * NPOS) return;
  int b = idx / NPOS, n = idx % NPOS;
  const float* xb = x0 + b * CA * NPOS;
  float q[CA];
  #pragma unroll
  for (int c = 0; c < CA; c++) {
    float s = bq[c];
    #pragma unroll
    for (int cc = 0; cc < CA; cc++) s += wq[c * CA + cc] * xb[cc * NPOS + n];
    q[c] = s;
  }
  float mrun = -1e30f, lrun = 0.f, acc[CA] = {0, 0, 0, 0, 0};
  for (int m = 0; m < NPOS; m++) {
    float xm[CA];
    #pragma unroll
    for (int cc = 0; cc < CA; cc++) xm[cc] = xb[cc * NPOS + m];
    float e = 0.f;
    #pragma unroll
    for (int c = 0; c < CA; c++) {
      float kk = bk[c];
      #pragma unroll
      for (int cc = 0; cc < CA; cc++) kk += wk[c * CA + cc] * xm[cc];
      e += q[c] * kk;
    }
    float nm = fmaxf(mrun, e);
    float corr = __expf(mrun - nm);
    float pp = __expf(e - nm);
    lrun = lrun * corr + pp;
    #pragma unroll
    for (int c = 0; c < CA; c++) {
      float vv = bv[c];
      #pragma unroll
      for (int cc = 0; cc < CA; cc++) vv += wv[c * CA + cc] * xm[cc];
      acc[c] = acc[c] * corr + pp * vv;
    }
    mrun = nm;
  }
  float invl = 1.f / lrun;
  #pragma unroll
  for (int c = 0; c < CA; c++)
    out1[b * CA * NPOS + c * NPOS + n] = gamma * (acc[c] * invl) + xb[c * NPOS + n];
}

__device__ __forceinline__ float x2_load(const float* __restrict__ out1, int b, int c, int n2) {
  int h = n2 / 123, w = n2 - h * 123;
  return out1[((b * CA + c) * 123 + w) * 32 + h];
}

__global__ void k_attn2(const float* __restrict__ out1, float* __restrict__ flat,
                        const float* __restrict__ wq, const float* __restrict__ bq,
                        const float* __restrict__ wk, const float* __restrict__ bk,
                        const float* __restrict__ wv, const float* __restrict__ bv,
                        const float* __restrict__ gamma_p, const float* __restrict__ gamma1_p) {
  float gamma = gamma_p[0];
  if (gamma == 0.f && gamma1_p[0] == 0.f) return;   // fused fast path already done
  int idx = blockIdx.x * 256 + threadIdx.x;
  if (gamma == 0.f) {                               // transpose copy into flat
    if (idx < OUT0_ELEMS) {
      int b = idx / FLAT_K;
      int r = idx - b * FLAT_K;
      int c = r / NPOS;
      int n2 = r - c * NPOS;
      flat[idx] = x2_load(out1, b, c, n2);
    }
    return;
  }
  if (idx >= B * NPOS) return;
  int b = idx / NPOS, n = idx % NPOS;
  float q[CA];
  #pragma unroll
  for (int c = 0; c < CA; c++) {
    float s = bq[c];
    #pragma unroll
    for (int cc = 0; cc < CA; cc++) s += wq[c * CA + cc] * x2_load(out1, b, cc, n);
    q[c] = s;
  }
  float mrun = -1e30f, lrun = 0.f, acc[CA] = {0, 0, 0, 0, 0};
  for (int m = 0; m < NPOS; m++) {
    float xm[CA];
    #pragma unroll
    for (int cc = 0; cc < CA; cc++) xm[cc] = x2_load(out1, b, cc, m);
    float e = 0.f;
    #pragma unroll
    for (int c = 0; c < CA; c++) {
      float kk = bk[c];
      #pragma unroll
      for (int cc = 0; cc < CA; cc++) kk += wk[c * CA + cc] * xm[cc];
      e += q[c] * kk;
    }
    float nm = fmaxf(mrun, e);
    float corr = __expf(mrun - nm);
    float pp = __expf(e - nm);
    lrun = lrun * corr + pp;
    #pragma unroll
    for (int c = 0; c < CA; c++) {
      float vv = bv[c];
      #pragma unroll
      for (int cc = 0; cc < CA; cc++) vv += wv[c * CA + cc] * xm[cc];
      acc[c] = acc[c] * corr + pp * vv;
    }
    mrun = nm;
  }
  float invl = 1.f / lrun;
  #pragma unroll
  for (int c = 0; c < CA; c++)
    flat[b * FLAT_K + c * NPOS + n] = gamma * (acc[c] * invl) + x2_load(out1, b, c, n);
}

// ---------------- fc1 split-K: stage A partials ----------------
// grid (256 o-groups, KSPLIT), block 256. part[kc][o][b]
__global__ __launch_bounds__(256) void k_fc1_part(const float* __restrict__ flat,
                                                  const float* __restrict__ w,
                                                  float* __restrict__ part) {
  int tid = threadIdx.x;
  int o0 = blockIdx.x * 4;
  int kc = blockIdx.y;
  int kbeg = kc * KCHUNK, kend = kbeg + KCHUNK;
  float acc[4][16];
  #pragma unroll
  for (int o = 0; o < 4; o++)
    #pragma unroll
    for (int b = 0; b < 16; b++) acc[o][b] = 0.f;

  for (int k = kbeg + tid * 4; k < kend; k += 1024) {
    float4 wv[4];
    #pragma unroll
    for (int o = 0; o < 4; o++)
      wv[o] = *(const float4*)(w + (size_t)(o0 + o) * FLAT_K + k);
    #pragma unroll
    for (int b = 0; b < 16; b++) {
      float4 f = *(const float4*)(flat + b * FLAT_K + k);
      #pragma unroll
      for (int o = 0; o < 4; o++)
        acc[o][b] += f.x * wv[o].x + f.y * wv[o].y + f.z * wv[o].z + f.w * wv[o].w;
    }
  }
  // full-wave butterfly so lane o*16+b holds the wave total
  #pragma unroll
  for (int o = 0; o < 4; o++)
    #pragma unroll
    for (int b = 0; b < 16; b++)
      #pragma unroll
      for (int off = 1; off < 64; off <<= 1)
        acc[o][b] += __shfl_xor(acc[o][b], off);

  __shared__ float red[4][64];
  int lane = tid & 63, wv_ = tid >> 6;
  #pragma unroll
  for (int o = 0; o < 4; o++)
    #pragma unroll
    for (int b = 0; b < 16; b++)
      if (lane == o * 16 + b) red[wv_][o * 16 + b] = acc[o][b];
  __syncthreads();

  if (tid < 64) {
    float s = red[0][tid] + red[1][tid] + red[2][tid] + red[3][tid];
    int o = o0 + (tid >> 4), b = tid & 15;
    part[(kc * F1 + o) * 16 + b] = s;
  }
}

// ---------------- fc1 stage B: reduce partials + bias + bn6(batch) + elu ----------------
__global__ void k_fc1_finish(const float* __restrict__ part, const float* __restrict__ bias,
                             const float* __restrict__ g6, const float* __restrict__ b6,
                             float* __restrict__ hact) {
  int g = blockIdx.x * 256 + threadIdx.x;   // 64 blocks
  int o = g >> 4, b = g & 15;
  float s = 0.f;
  #pragma unroll
  for (int kc = 0; kc < KSPLIT; kc++) s += part[(kc * F1 + o) * 16 + b];
  float h = s + bias[o];
  float sum = h, sq = h * h;
  #pragma unroll
  for (int off = 1; off < 16; off <<= 1) {
    sum += __shfl_xor(sum, off);
    sq  += __shfl_xor(sq, off);
  }
  float mean = sum * (1.f / 16.f);
  float var  = sq * (1.f / 16.f) - mean * mean;
  float a = (h - mean) * rsqrtf(var + 1e-5f) * g6[o] + b6[o];
  hact[b * F1 + o] = elu1(a);
}

// ---------------- fc2 (1024 -> 13) + softmax ----------------
__global__ void k_fc2(const float* __restrict__ hact, const float* __restrict__ w2,
                      const float* __restrict__ b2, float* __restrict__ out) {
  int b = blockIdx.x, tid = threadIdx.x;   // block 256
  float acc[13];
  #pragma unroll
  for (int c = 0; c < 13; c++) acc[c] = 0.f;
  const float* hb = hact + b * F1;
  for (int k = tid; k < F1; k += 256) {
    float hv = hb[k];
    #pragma unroll
    for (int c = 0; c < 13; c++) acc[c] += hv * w2[c * F1 + k];
  }
  #pragma unroll
  for (int c = 0; c < 13; c++)
    #pragma unroll
    for (int off = 1; off < 64; off <<= 1)
      acc[c] += __shfl_xor(acc[c], off);
  __shared__ float red[4][13];
  int lane = tid & 63, w = tid >> 6;
  if (lane == 0) {
    #pragma unroll
    for (int c = 0; c < 13; c++) red[w][c] = acc[c];
  }
  __syncthreads();
  if (tid == 0) {
    float logit[13];
    float mx = -1e30f;
    #pragma unroll
    for (int c = 0; c < 13; c++) {
      logit[c] = red[0][c] + red[1][c] + red[2][c] + red[3][c] + b2[c];
      mx = fmaxf(mx, logit[c]);
    }
    float s = 0.f;
    #pragma unroll
    for (int c = 0; c < 13; c++) { logit[c] = expf(logit[c] - mx); s += logit[c]; }
    float inv = 1.f / s;
    #pragma unroll
    for (int c = 0; c < 13; c++) out[b * 13 + c] = logit[c] * inv;
  }
}

// ---------------- launch ----------------
extern "C" void kernel_launch(void* const* d_in, const int* in_sizes, int n_in,
                              void* d_out, int out_size, void* d_ws, size_t ws_size,
                              hipStream_t stream) {
  const float* x     = (const float*)d_in[0];
  const float* c1_w  = (const float*)d_in[1];
  const float* c1_b  = (const float*)d_in[2];
  const float* bn1_g = (const float*)d_in[3];
  const float* bn1_b = (const float*)d_in[4];
  const float* c4_w  = (const float*)d_in[5];
  const float* c4_b  = (const float*)d_in[6];
  const float* bn4_g = (const float*)d_in[7];
  const float* bn4_b = (const float*)d_in[8];
  const float* c5_w  = (const float*)d_in[9];
  const float* c5_b  = (const float*)d_in[10];
  const float* bn5_g = (const float*)d_in[11];
  const float* bn5_b = (const float*)d_in[12];
  const float* a1_wq = (const float*)d_in[13];
  const float* a1_bq = (const float*)d_in[14];
  const float* a1_wk = (const float*)d_in[15];
  const float* a1_bk = (const float*)d_in[16];
  const float* a1_wv = (const float*)d_in[17];
  const float* a1_bv = (const float*)d_in[18];
  const float* a1_ga = (const float*)d_in[19];
  const float* a2_wq = (const float*)d_in[20];
  const float* a2_bq = (const float*)d_in[21];
  const float* a2_wk = (const float*)d_in[22];
  const float* a2_bk = (const float*)d_in[23];
  const float* a2_wv = (const float*)d_in[24];
  const float* a2_bv = (const float*)d_in[25];
  const float* a2_ga = (const float*)d_in[26];
  const float* fc1_w = (const float*)d_in[27];
  const float* fc1_b = (const float*)d_in[28];
  const float* bn6_g = (const float*)d_in[29];
  const float* bn6_b = (const float*)d_in[30];
  const float* fc2_w = (const float*)d_in[31];
  const float* fc2_b = (const float*)d_in[32];

  float* ws    = (float*)d_ws;
  float* stats = ws;
  float* y1    = ws + STATS_FLOATS;
  float* p1    = y1 + B * C1 * L1;
  float* y4    = p1 + B * C1 * LP1;
  float* p4    = y4 + B * C4 * L4;
  float* y5    = p4 + B * C4 * LP4;
  float* out0  = y5 + B * C5 * L5;
  float* out1  = out0 + OUT0_ELEMS;
  float* flat  = out1 + OUT0_ELEMS;
  float* hact  = flat + OUT0_ELEMS;
  float* part  = hact + B * F1;        // KSPLIT*1024*16 floats

  hipMemsetAsync(stats, 0, STATS_FLOATS * sizeof(float), stream);

  k_conv1<<<dim3(2, C1, B), 256, 0, stream>>>(x, c1_w, c1_b, y1, stats);
  k_bnpool<<<dim3(1, C1, B), 256, 0, stream>>>(y1, p1, bn1_g, bn1_b,
                                               stats + S1_SUM, stats + S1_SQ,
                                               C1, L1, LP1, 1.f / N1);
  k_conv4<<<dim3(1, C4, B), 256, 0, stream>>>(p1, c4_w, c4_b, y4, stats);
  k_bnpool<<<dim3(1, C4, B), 128, 0, stream>>>(y4, p4, bn4_g, bn4_b,
                                               stats + S4_SUM, stats + S4_SQ,
                                               C4, L4, LP4, 1.f / N4);
  k_conv5<<<dim3(1, C5, B), 128, 0, stream>>>(p4, c5_w, c5_b, y5, stats);
  k_tail<<<(OUT0_ELEMS + 255) / 256, 256, 0, stream>>>(y5, out0, flat, bn5_g, bn5_b,
                                                       stats, a1_ga, a2_ga);
  k_attn1<<<(OUT0_ELEMS + 255) / 256, 256, 0, stream>>>(out0, out1, a1_wq, a1_bq,
                                                        a1_wk, a1_bk, a1_wv, a1_bv,
                                                        a1_ga, a2_ga);
  k_attn2<<<(OUT0_ELEMS + 255) / 256, 256, 0, stream>>>(out1, flat, a2_wq, a2_bq,
                                                        a2_wk, a2_bk, a2_wv, a2_bv,
                                                        a2_ga, a1_ga);
  k_fc1_part<<<dim3(F1 / 4, KSPLIT), 256, 0, stream>>>(flat, fc1_w, part);
  k_fc1_finish<<<F1 * 16 / 256, 256, 0, stream>>>(part, fc1_b, bn6_g, bn6_b, hact);
  k_fc2<<<B, 256, 0, stream>>>(hact, fc2_w, fc2_b, (float*)d_out);
}

// Round 5
// 225.452 us; speedup vs baseline: 1.9018x; 1.9018x over previous
//
#include <hip/hip_runtime.h>
#include <hip/hip_bf16.h>

// ---------------- sizes ----------------
#define B 16
#define L1 509
#define C1 32
#define N1 (B*L1)
#define LP1 254
#define L4 250
#define C4 64
#define N4 (B*L4)
#define LP4 125
#define L5 123
#define C5 32
#define N5 (B*L5)
#define NPOS 3936
#define CA 5
#define OUT0_ELEMS (B*CA*NPOS)   // 314880
#define FLAT_K 19680
#define F1 1024
// fc1 split-K
#define KSPLIT 8
#define KCHUNK 2460              // 19680/8
#define OBLK 32                  // outputs per block
#define OWAVE 4                  // outputs per wave

// ---------------- ws layout (floats) ----------------
#define P1S 0
#define P1Q 1024
#define P4S 2048
#define P4Q 3072
#define P5S 4096
#define P5Q 4608
#define WSBUF 5120

// ---------------- helpers ----------------
__device__ __forceinline__ float elu1(float x) {
  return x > 0.f ? x : (expf(x) - 1.f);
}

// block-wide reduction of (v1,v2), thread 0 stores to slot (no atomics).
__device__ __forceinline__ void block_reduce2_store(float v1, float v2, float* d1, float* d2) {
  #pragma unroll
  for (int off = 32; off > 0; off >>= 1) {
    v1 += __shfl_down(v1, off);
    v2 += __shfl_down(v2, off);
  }
  __shared__ float s1[8], s2[8];
  int lane = threadIdx.x & 63, w = threadIdx.x >> 6;
  if (lane == 0) { s1[w] = v1; s2[w] = v2; }
  __syncthreads();
  if (threadIdx.x == 0) {
    int nw = (blockDim.x + 63) >> 6;
    float a = 0.f, bb = 0.f;
    for (int i = 0; i < nw; i++) { a += s1[i]; bb += s2[i]; }
    *d1 = a; *d2 = bb;
  }
}

// ---------------- conv stages ----------------
__global__ void k_conv1(const float* __restrict__ x, const float* __restrict__ w,
                        const float* __restrict__ bias, float* __restrict__ y1,
                        float* __restrict__ ws) {
  int l = blockIdx.x * blockDim.x + threadIdx.x;
  int co = blockIdx.y, b = blockIdx.z;
  float v = 0.f;
  if (l < L1) {
    v = bias[co];
    const float* xp = x + b * 5 * 1021;
    const float* wp = w + co * 25;
    #pragma unroll
    for (int ci = 0; ci < 5; ci++)
      #pragma unroll
      for (int t = 0; t < 5; t++)
        v += xp[ci * 1021 + 2 * l + t] * wp[ci * 5 + t];
    y1[(b * C1 + co) * L1 + l] = v;
  }
  int slot = blockIdx.z * 2 + blockIdx.x;    // 32 slots per channel
  block_reduce2_store(v, v * v, &ws[P1S + co * 32 + slot], &ws[P1Q + co * 32 + slot]);
}

__global__ void k_bnpool(const float* __restrict__ y, float* __restrict__ p,
                         const float* __restrict__ g, const float* __restrict__ be,
                         const float* __restrict__ psum, const float* __restrict__ psq,
                         int nslots, int C, int Lin, int Lout, float invN) {
  int co = blockIdx.y, b = blockIdx.z;
  __shared__ float msc[2];
  if (threadIdx.x == 0) {
    float s = 0.f, q = 0.f;
    for (int i = 0; i < nslots; i++) { s += psum[co * nslots + i]; q += psq[co * nslots + i]; }
    float mean = s * invN;
    float var  = q * invN - mean * mean;
    msc[0] = mean;
    msc[1] = rsqrtf(var + 1e-5f) * g[co];
  }
  __syncthreads();
  int i = blockIdx.x * blockDim.x + threadIdx.x;
  if (i >= Lout) return;
  float mean = msc[0], sc = msc[1], bb = be[co];
  const float* yp = y + (b * C + co) * Lin;
  float a0 = (yp[2 * i]     - mean) * sc + bb;
  float a1 = (yp[2 * i + 1] - mean) * sc + bb;
  p[(b * C + co) * Lout + i] = fmaxf(elu1(a0), elu1(a1));
}

__global__ void k_conv4(const float* __restrict__ p1, const float* __restrict__ w,
                        const float* __restrict__ bias, float* __restrict__ y4,
                        float* __restrict__ ws) {
  int l = threadIdx.x;  // block 256, 250 active
  int co = blockIdx.y, b = blockIdx.z;
  float v = 0.f;
  if (l < L4) {
    v = bias[co];
    const float* pp = p1 + b * C1 * LP1;
    const float* wp = w + co * (C1 * 5);
    for (int ci = 0; ci < C1; ci++) {
      #pragma unroll
      for (int t = 0; t < 5; t++)
        v += pp[ci * LP1 + l + t] * wp[ci * 5 + t];
    }
    y4[(b * C4 + co) * L4 + l] = v;
  }
  block_reduce2_store(v, v * v, &ws[P4S + co * 16 + blockIdx.z], &ws[P4Q + co * 16 + blockIdx.z]);
}

__global__ void k_conv5(const float* __restrict__ p4, const float* __restrict__ w,
                        const float* __restrict__ bias, float* __restrict__ y5,
                        float* __restrict__ ws) {
  int l = threadIdx.x;  // block 128, 123 active
  int co = blockIdx.y, b = blockIdx.z;
  float v = 0.f;
  if (l < L5) {
    v = bias[co];
    const float* pp = p4 + b * C4 * LP4;
    const float* wp = w + co * (C4 * 3);
    for (int ci = 0; ci < C4; ci++) {
      #pragma unroll
      for (int t = 0; t < 3; t++)
        v += pp[ci * LP4 + l + t] * wp[ci * 3 + t];
    }
    y5[(b * C5 + co) * L5 + l] = v;
  }
  block_reduce2_store(v, v * v, &ws[P5S + co * 16 + blockIdx.z], &ws[P5Q + co * 16 + blockIdx.z]);
}

// tail: if both gammas are 0, both attentions are identities -> write flat directly.
// flat[b, c*3936 + h*123 + w] = elu(bn5(y5[b,h,w]))   (broadcast over c)
// else build out0[b,c,w,h] for the generic attn kernels.
__global__ void k_tail(const float* __restrict__ y5, float* __restrict__ out0,
                       float* __restrict__ flat,
                       const float* __restrict__ g, const float* __restrict__ be,
                       const float* __restrict__ ws,
                       const float* __restrict__ ga1, const float* __restrict__ ga2) {
  __shared__ float sm[32], ss[32];
  if (threadIdx.x < 32) {
    int h = threadIdx.x;
    float s = 0.f, q = 0.f;
    for (int i = 0; i < 16; i++) { s += ws[P5S + h * 16 + i]; q += ws[P5Q + h * 16 + i]; }
    float mean = s * (1.f / N5);
    float var  = q * (1.f / N5) - mean * mean;
    sm[h] = mean;
    ss[h] = rsqrtf(var + 1e-5f) * g[h];
  }
  __syncthreads();
  int idx = blockIdx.x * 256 + threadIdx.x;
  if (idx >= OUT0_ELEMS) return;
  bool fast = (ga1[0] == 0.f) && (ga2[0] == 0.f);
  if (fast) {
    int b = idx / FLAT_K;
    int r = idx - b * FLAT_K;
    int n2 = r % NPOS;
    int h = n2 / 123;
    int w_ = n2 - h * 123;
    float v = (y5[(b * C5 + h) * L5 + w_] - sm[h]) * ss[h] + be[h];
    flat[idx] = elu1(v);
  } else {
    int h = idx & 31;
    int rest = idx >> 5;
    int w_ = rest % 123;
    int bc = rest / 123;
    int b = bc / 5;
    float v = (y5[(b * C5 + h) * L5 + w_] - sm[h]) * ss[h] + be[h];
    out0[idx] = elu1(v);
  }
}

// ---------------- generic attention (only runs when a gamma != 0) ----------------
__global__ void k_attn1(const float* __restrict__ x0, float* __restrict__ out1,
                        const float* __restrict__ wq, const float* __restrict__ bq,
                        const float* __restrict__ wk, const float* __restrict__ bk,
                        const float* __restrict__ wv, const float* __restrict__ bv,
                        const float* __restrict__ gamma_p, const float* __restrict__ gamma2_p) {
  float gamma = gamma_p[0];
  if (gamma == 0.f && gamma2_p[0] == 0.f) return;
  int idx = blockIdx.x * 256 + threadIdx.x;
  if (gamma == 0.f) {
    if (idx < OUT0_ELEMS) out1[idx] = x0[idx];
    return;
  }
  if (idx >= B * NPOS) return;
  int b = idx / NPOS, n = idx % NPOS;
  const float* xb = x0 + b * CA * NPOS;
  float q[CA];
  #pragma unroll
  for (int c = 0; c < CA; c++) {
    float s = bq[c];
    #pragma unroll
    for (int cc = 0; cc < CA; cc++) s += wq[c * CA + cc] * xb[cc * NPOS + n];
    q[c] = s;
  }
  float mrun = -1e30f, lrun = 0.f, acc[CA] = {0, 0, 0, 0, 0};
  for (int m = 0; m < NPOS; m++) {
    float xm[CA];
    #pragma unroll
    for (int cc = 0; cc < CA; cc++) xm[cc] = xb[cc * NPOS + m];
    float e = 0.f;
    #pragma unroll
    for (int c = 0; c < CA; c++) {
      float kk = bk[c];
      #pragma unroll
      for (int cc = 0; cc < CA; cc++) kk += wk[c * CA + cc] * xm[cc];
      e += q[c] * kk;
    }
    float nm = fmaxf(mrun, e);
    float corr = __expf(mrun - nm);
    float pp = __expf(e - nm);
    lrun = lrun * corr + pp;
    #pragma unroll
    for (int c = 0; c < CA; c++) {
      float vv = bv[c];
      #pragma unroll
      for (int cc = 0; cc < CA; cc++) vv += wv[c * CA + cc] * xm[cc];
      acc[c] = acc[c] * corr + pp * vv;
    }
    mrun = nm;
  }
  float invl = 1.f / lrun;
  #pragma unroll
  for (int c = 0; c < CA; c++)
    out1[b * CA * NPOS + c * NPOS + n] = gamma * (acc[c] * invl) + xb[c * NPOS + n];
}

__device__ __forceinline__ float x2_load(const float* __restrict__ out1, int b, int c, int n2) {
  int h = n2 / 123, w = n2 - h * 123;
  return out1[((b * CA + c) * 123 + w) * 32 + h];
}

__global__ void k_attn2(const float* __restrict__ out1, float* __restrict__ flat,
                        const float* __restrict__ wq, const float* __restrict__ bq,
                        const float* __restrict__ wk, const float* __restrict__ bk,
                        const float* __restrict__ wv, const float* __restrict__ bv,
                        const float* __restrict__ gamma_p, const float* __restrict__ gamma1_p) {
  float gamma = gamma_p[0];
  if (gamma == 0.f && gamma1_p[0] == 0.f) return;
  int idx = blockIdx.x * 256 + threadIdx.x;
  if (gamma == 0.f) {
    if (idx < OUT0_ELEMS) {
      int b = idx / FLAT_K;
      int r = idx - b * FLAT_K;
      int c = r / NPOS;
      int n2 = r - c * NPOS;
      flat[idx] = x2_load(out1, b, c, n2);
    }
    return;
  }
  if (idx >= B * NPOS) return;
  int b = idx / NPOS, n = idx % NPOS;
  float q[CA];
  #pragma unroll
  for (int c = 0; c < CA; c++) {
    float s = bq[c];
    #pragma unroll
    for (int cc = 0; cc < CA; cc++) s += wq[c * CA + cc] * x2_load(out1, b, cc, n);
    q[c] = s;
  }
  float mrun = -1e30f, lrun = 0.f, acc[CA] = {0, 0, 0, 0, 0};
  for (int m = 0; m < NPOS; m++) {
    float xm[CA];
    #pragma unroll
    for (int cc = 0; cc < CA; cc++) xm[cc] = x2_load(out1, b, cc, m);
    float e = 0.f;
    #pragma unroll
    for (int c = 0; c < CA; c++) {
      float kk = bk[c];
      #pragma unroll
      for (int cc = 0; cc < CA; cc++) kk += wk[c * CA + cc] * xm[cc];
      e += q[c] * kk;
    }
    float nm = fmaxf(mrun, e);
    float corr = __expf(mrun - nm);
    float pp = __expf(e - nm);
    lrun = lrun * corr + pp;
    #pragma unroll
    for (int c = 0; c < CA; c++) {
      float vv = bv[c];
      #pragma unroll
      for (int cc = 0; cc < CA; cc++) vv += wv[c * CA + cc] * xm[cc];
      acc[c] = acc[c] * corr + pp * vv;
    }
    mrun = nm;
  }
  float invl = 1.f / lrun;
  #pragma unroll
  for (int c = 0; c < CA; c++)
    flat[b * FLAT_K + c * NPOS + n] = gamma * (acc[c] * invl) + x2_load(out1, b, c, n);
}

// ---------------- fc1 split-K with LDS-staged activations ----------------
// grid (32 o-groups, KSPLIT=8) = 256 blocks, 512 threads (8 waves).
// Wave w owns 4 outputs; block owns 32 outputs x KCHUNK. flat[16][KCHUNK] in LDS.
// Only global stream = weights, prefetched one step ahead, coalesced float4.
__global__ __launch_bounds__(512) void k_fc1_part(const float* __restrict__ flat,
                                                  const float* __restrict__ w,
                                                  float* __restrict__ part) {
  extern __shared__ float lds[];            // 16 * KCHUNK floats = 157,440 B
  const int tid = threadIdx.x;
  const int kc = blockIdx.y;
  const int kbeg = kc * KCHUNK;

  // stage flat[16][KCHUNK] into LDS (float4, coalesced)
  #pragma unroll 1
  for (int b = 0; b < 16; b++) {
    const float4* src = (const float4*)(flat + b * FLAT_K + kbeg);
    float4* dst = (float4*)(lds + b * KCHUNK);
    for (int j = tid; j < KCHUNK / 4; j += 512) dst[j] = src[j];
  }
  __syncthreads();

  const int wave = tid >> 6, lane = tid & 63;
  const int obase = blockIdx.x * OBLK + wave * OWAVE;
  const float* wrow0 = w + (size_t)obase * FLAT_K + kbeg;

  float acc[64];
  #pragma unroll
  for (int i = 0; i < 64; i++) acc[i] = 0.f;

  // prefetch step 0 weights
  float4 wnxt[4];
  {
    int k0 = lane * 4;
    #pragma unroll
    for (int o = 0; o < 4; o++)
      wnxt[o] = *(const float4*)(wrow0 + o * FLAT_K + k0);
  }

  #pragma unroll 1
  for (int s = 0; s < 10; s++) {          // 10 steps of 256 k-elems (last ragged)
    float4 wcur[4];
    #pragma unroll
    for (int o = 0; o < 4; o++) wcur[o] = wnxt[o];
    if (s < 9) {
      int kn = (s + 1) * 256 + lane * 4;
      if (kn >= KCHUNK) kn = 0;           // clamp (in-bounds, result unused)
      #pragma unroll
      for (int o = 0; o < 4; o++)
        wnxt[o] = *(const float4*)(wrow0 + o * FLAT_K + kn);
    }
    int kcur = s * 256 + lane * 4;
    if (kcur < KCHUNK) {
      #pragma unroll
      for (int b = 0; b < 16; b++) {
        float4 f = *(const float4*)(lds + b * KCHUNK + kcur);
        #pragma unroll
        for (int o = 0; o < 4; o++)
          acc[o * 16 + b] += f.x * wcur[o].x + f.y * wcur[o].y +
                             f.z * wcur[o].z + f.w * wcur[o].w;
      }
    }
  }

  // transpose-reduce: 64 values x 64 lanes -> lane l holds total of flat index l
  #pragma unroll
  for (int round = 0; round < 6; round++) {
    const int bit = 1 << round;
    const int half = 32 >> round;         // surviving pairs this round
    #pragma unroll
    for (int i = 0; i < 32; i++) {
      if (i < half) {
        bool hi = (lane & bit) != 0;
        float keep  = hi ? acc[2 * i + 1] : acc[2 * i];
        float other = hi ? acc[2 * i]     : acc[2 * i + 1];
        acc[i] = keep + __shfl_xor(other, bit);
      }
    }
  }
  // lane l: value for (o = l>>4, b = l&15)
  part[((size_t)kc * F1 + obase + (lane >> 4)) * 16 + (lane & 15)] = acc[0];
}

// ---------------- fc1 stage B: reduce partials + bias + bn6(batch) + elu ----------------
__global__ void k_fc1_finish(const float* __restrict__ part, const float* __restrict__ bias,
                             const float* __restrict__ g6, const float* __restrict__ b6,
                             float* __restrict__ hact) {
  int g = blockIdx.x * 256 + threadIdx.x;
  int o = g >> 4, b = g & 15;
  float s = 0.f;
  #pragma unroll
  for (int kc = 0; kc < KSPLIT; kc++) s += part[(kc * F1 + o) * 16 + b];
  float h = s + bias[o];
  float sum = h, sq = h * h;
  #pragma unroll
  for (int off = 1; off < 16; off <<= 1) {
    sum += __shfl_xor(sum, off);
    sq  += __shfl_xor(sq, off);
  }
  float mean = sum * (1.f / 16.f);
  float var  = sq * (1.f / 16.f) - mean * mean;
  float a = (h - mean) * rsqrtf(var + 1e-5f) * g6[o] + b6[o];
  hact[b * F1 + o] = elu1(a);
}

// ---------------- fc2 (1024 -> 13) + softmax ----------------
__global__ void k_fc2(const float* __restrict__ hact, const float* __restrict__ w2,
                      const float* __restrict__ b2, float* __restrict__ out) {
  int b = blockIdx.x, tid = threadIdx.x;   // block 256
  float acc[13];
  #pragma unroll
  for (int c = 0; c < 13; c++) acc[c] = 0.f;
  const float* hb = hact + b * F1;
  for (int k = tid; k < F1; k += 256) {
    float hv = hb[k];
    #pragma unroll
    for (int c = 0; c < 13; c++) acc[c] += hv * w2[c * F1 + k];
  }
  #pragma unroll
  for (int c = 0; c < 13; c++)
    #pragma unroll
    for (int off = 1; off < 64; off <<= 1)
      acc[c] += __shfl_xor(acc[c], off);
  __shared__ float red[4][13];
  int lane = tid & 63, w = tid >> 6;
  if (lane == 0) {
    #pragma unroll
    for (int c = 0; c < 13; c++) red[w][c] = acc[c];
  }
  __syncthreads();
  if (tid == 0) {
    float logit[13];
    float mx = -1e30f;
    #pragma unroll
    for (int c = 0; c < 13; c++) {
      logit[c] = red[0][c] + red[1][c] + red[2][c] + red[3][c] + b2[c];
      mx = fmaxf(mx, logit[c]);
    }
    float s = 0.f;
    #pragma unroll
    for (int c = 0; c < 13; c++) { logit[c] = expf(logit[c] - mx); s += logit[c]; }
    float inv = 1.f / s;
    #pragma unroll
    for (int c = 0; c < 13; c++) out[b * 13 + c] = logit[c] * inv;
  }
}

// ---------------- launch ----------------
extern "C" void kernel_launch(void* const* d_in, const int* in_sizes, int n_in,
                              void* d_out, int out_size, void* d_ws, size_t ws_size,
                              hipStream_t stream) {
  const float* x     = (const float*)d_in[0];
  const float* c1_w  = (const float*)d_in[1];
  const float* c1_b  = (const float*)d_in[2];
  const float* bn1_g = (const float*)d_in[3];
  const float* bn1_b = (const float*)d_in[4];
  const float* c4_w  = (const float*)d_in[5];
  const float* c4_b  = (const float*)d_in[6];
  const float* bn4_g = (const float*)d_in[7];
  const float* bn4_b = (const float*)d_in[8];
  const float* c5_w  = (const float*)d_in[9];
  const float* c5_b  = (const float*)d_in[10];
  const float* bn5_g = (const float*)d_in[11];
  const float* bn5_b = (const float*)d_in[12];
  const float* a1_wq = (const float*)d_in[13];
  const float* a1_bq = (const float*)d_in[14];
  const float* a1_wk = (const float*)d_in[15];
  const float* a1_bk = (const float*)d_in[16];
  const float* a1_wv = (const float*)d_in[17];
  const float* a1_bv = (const float*)d_in[18];
  const float* a1_ga = (const float*)d_in[19];
  const float* a2_wq = (const float*)d_in[20];
  const float* a2_bq = (const float*)d_in[21];
  const float* a2_wk = (const float*)d_in[22];
  const float* a2_bk = (const float*)d_in[23];
  const float* a2_wv = (const float*)d_in[24];
  const float* a2_bv = (const float*)d_in[25];
  const float* a2_ga = (const float*)d_in[26];
  const float* fc1_w = (const float*)d_in[27];
  const float* fc1_b = (const float*)d_in[28];
  const float* bn6_g = (const float*)d_in[29];
  const float* bn6_b = (const float*)d_in[30];
  const float* fc2_w = (const float*)d_in[31];
  const float* fc2_b = (const float*)d_in[32];

  float* ws    = (float*)d_ws;
  float* y1    = ws + WSBUF;
  float* p1    = y1 + B * C1 * L1;
  float* y4    = p1 + B * C1 * LP1;
  float* p4    = y4 + B * C4 * L4;
  float* y5    = p4 + B * C4 * LP4;
  float* out0  = y5 + B * C5 * L5;
  float* out1  = out0 + OUT0_ELEMS;
  float* flat  = out1 + OUT0_ELEMS;
  float* hact  = flat + OUT0_ELEMS;
  float* part  = hact + B * F1;        // KSPLIT*1024*16 floats

  // allow >64KB dynamic LDS for fc1_part (idempotent; ignore errors)
  hipFuncSetAttribute((const void*)k_fc1_part,
                      hipFuncAttributeMaxDynamicSharedMemorySize,
                      16 * KCHUNK * 4);

  k_conv1<<<dim3(2, C1, B), 256, 0, stream>>>(x, c1_w, c1_b, y1, ws);
  k_bnpool<<<dim3(1, C1, B), 256, 0, stream>>>(y1, p1, bn1_g, bn1_b,
                                               ws + P1S, ws + P1Q,
                                               32, C1, L1, LP1, 1.f / N1);
  k_conv4<<<dim3(1, C4, B), 256, 0, stream>>>(p1, c4_w, c4_b, y4, ws);
  k_bnpool<<<dim3(1, C4, B), 128, 0, stream>>>(y4, p4, bn4_g, bn4_b,
                                               ws + P4S, ws + P4Q,
                                               16, C4, L4, LP4, 1.f / N4);
  k_conv5<<<dim3(1, C5, B), 128, 0, stream>>>(p4, c5_w, c5_b, y5, ws);
  k_tail<<<(OUT0_ELEMS + 255) / 256, 256, 0, stream>>>(y5, out0, flat, bn5_g, bn5_b,
                                                       ws, a1_ga, a2_ga);
  k_attn1<<<(OUT0_ELEMS + 255) / 256, 256, 0, stream>>>(out0, out1, a1_wq, a1_bq,
                                                        a1_wk, a1_bk, a1_wv, a1_bv,
                                                        a1_ga, a2_ga);
  k_attn2<<<(OUT0_ELEMS + 255) / 256, 256, 0, stream>>>(out1, flat, a2_wq, a2_bq,
                                                        a2_wk, a2_bk, a2_wv, a2_bv,
                                                        a2_ga, a1_ga);
  k_fc1_part<<<dim3(F1 / OBLK, KSPLIT), 512, 16 * KCHUNK * 4, stream>>>(flat, fc1_w, part);
  k_fc1_finish<<<F1 * 16 / 256, 256, 0, stream>>>(part, fc1_b, bn6_g, bn6_b, hact);
  k_fc2<<<B, 256, 0, stream>>>(hact, fc2_w, fc2_b, (float*)d_out);
}